// Round 6
// baseline (983.263 us; speedup 1.0000x reference)
//
#include <hip/hip_runtime.h>

#define NN 20000      // nodes
#define NE 200000     // edges
#define NH1 256       // H*C layer1
#define ED 384
#define NG 64
#define NCLS 751
#define ETOT (NE + NN)   // 220000 edges incl self loops

typedef unsigned short u16;
typedef __attribute__((ext_vector_type(8))) short short8;
typedef __attribute__((ext_vector_type(4))) float f32x4;

__device__ __forceinline__ float bf2f(u16 u){
  union { unsigned int i; float f; } v; v.i = ((unsigned int)u) << 16; return v.f;
}
__device__ __forceinline__ u16 f2bf(float f){
  union { float f; unsigned int i; } v; v.f = f;
  return (u16)((v.i + 0x7fffu + ((v.i >> 16) & 1u)) >> 16);
}

// ---------- prep kernels ----------
__global__ void transpose_k(const float* __restrict__ in, u16* __restrict__ out, int K, int N){
  int idx = blockIdx.x * 256 + threadIdx.x;
  if (idx >= K * N) return;
  int k = idx / N, n = idx - k * N;
  out[n * K + k] = f2bf(in[idx]);
}

// straight f32 -> bf16, 8 elems/thread
__global__ void convx_k(const float* __restrict__ in, u16* __restrict__ out, int total8){
  int idx = blockIdx.x * 256 + threadIdx.x;
  if (idx >= total8) return;
  const float4* p = (const float4*)in + (size_t)idx * 2;
  float4 f0 = p[0], f1 = p[1];
  union { u16 h[8]; uint4 v; } pk;
  pk.h[0] = f2bf(f0.x); pk.h[1] = f2bf(f0.y); pk.h[2] = f2bf(f0.z); pk.h[3] = f2bf(f0.w);
  pk.h[4] = f2bf(f1.x); pk.h[5] = f2bf(f1.y); pk.h[6] = f2bf(f1.z); pk.h[7] = f2bf(f1.w);
  ((uint4*)out)[idx] = pk.v;
}

__global__ void concatbias_k(const float* __restrict__ b1l, const float* __restrict__ b1r,
                             const float* __restrict__ b2l, const float* __restrict__ b2r,
                             float* __restrict__ biasLR1, float* __restrict__ biasLR2){
  int i = blockIdx.x * 256 + threadIdx.x;
  if (i < 256) biasLR1[i] = b1l[i];
  else if (i < 512) biasLR1[i] = b1r[i - 256];
  else if (i < 576) biasLR2[i - 512] = b2l[i - 512];
  else if (i < 640) biasLR2[i - 512] = b2r[i - 576];
}

__global__ void hist_k(const int* __restrict__ rowA, const int* __restrict__ colA,
                       int* __restrict__ degR, int* __restrict__ degC){
  int e = blockIdx.x * 256 + threadIdx.x;
  if (e >= NE) return;
  atomicAdd(&degR[rowA[e]], 1);
  atomicAdd(&degC[colA[e]], 1);
}

__global__ void scan_k(const int* __restrict__ degR, const int* __restrict__ degC,
                       int* __restrict__ rowPtr, int* __restrict__ colPtr){
  __shared__ int sR[256], sC[256];
  int t = threadIdx.x;
  const int chunk = (NN + 255) / 256;
  int beg = t * chunk, end = min(beg + chunk, NN);
  int aR = 0, aC = 0;
  for (int i = beg; i < end; i++){ aR += degR[i]; aC += degC[i]; }
  sR[t] = aR; sC[t] = aC;
  __syncthreads();
  for (int off = 1; off < 256; off <<= 1){
    int vR = 0, vC = 0;
    if (t >= off){ vR = sR[t - off]; vC = sC[t - off]; }
    __syncthreads();
    sR[t] += vR; sC[t] += vC;
    __syncthreads();
  }
  int rR = (t == 0) ? 0 : sR[t - 1];
  int rC = (t == 0) ? 0 : sC[t - 1];
  for (int i = beg; i < end; i++){
    rowPtr[i] = rR; rR += degR[i];
    colPtr[i] = rC; rC += degC[i];
  }
  if (t == 255){ rowPtr[NN] = sR[255]; colPtr[NN] = sC[255]; }
}

__global__ void scatter_k(const int* __restrict__ rowA, const int* __restrict__ colA,
                          const int* __restrict__ rowPtr, const int* __restrict__ colPtr,
                          int* __restrict__ rowCur, int* __restrict__ colCur,
                          int* __restrict__ rowIdx, int* __restrict__ colIdx){
  int e = blockIdx.x * 256 + threadIdx.x;
  if (e >= NE) return;
  int r = rowA[e]; int p = atomicAdd(&rowCur[r], 1); rowIdx[rowPtr[r] + p] = e;
  int c = colA[e]; int q = atomicAdd(&colCur[c], 1); colIdx[colPtr[c] + q] = e;
}

// loop_attr + fused eattr->bf16 conversion (each edge appears once in col-CSR)
__global__ __launch_bounds__(256) void loopattr_k(const int* __restrict__ colPtr,
                                                  const int* __restrict__ colIdx,
                                                  const float* __restrict__ eattr,
                                                  u16* __restrict__ ea16){
  int node = blockIdx.x * 4 + (threadIdx.x >> 6);
  if (node >= NN) return;
  int lane = threadIdx.x & 63;
  int p0 = colPtr[node], deg = colPtr[node + 1] - p0;
  float inv = 1.f / fmaxf((float)deg, 1.f);
  float s[6] = {0.f, 0.f, 0.f, 0.f, 0.f, 0.f};
  for (int t = 0; t < deg; t++){
    int e = colIdx[p0 + t];
    const float* rowp = eattr + (size_t)e * ED;
    u16* wp = ea16 + (size_t)e * ED;
    #pragma unroll
    for (int c0 = 0; c0 < 6; c0++){
      float v = rowp[c0 * 64 + lane];
      s[c0] += v;
      wp[c0 * 64 + lane] = f2bf(v);
    }
  }
  u16* outp = ea16 + (size_t)(NE + node) * ED;
  #pragma unroll
  for (int c0 = 0; c0 < 6; c0++) outp[c0 * 64 + lane] = f2bf(s[c0] * inv);
}

// ---------- node GEMM (bf16 A): C[M,Ntot] = A16[M,K] x B, bf16 out + f32 bias
// BN=128 (halves A re-reads, 16 MFMA : 10 ds_read per wave-iter).
// Distance-2 A prefetch (ping-pong named regs), distance-1 B prefetch.
// Requires K % 64 == 0, N-tile exactly 128. Loads unconditional; tail rows
// read into adjacent allocations (harmless, masked at the store).
__global__ __launch_bounds__(256)
void gemm_k(const u16* __restrict__ A16,
            const u16* __restrict__ Bt, int M, int K, int Ntot,
            const float* __restrict__ bias, u16* __restrict__ outBf)
{
  __shared__ __align__(16) u16 lA[128 * 40];
  __shared__ __align__(16) u16 lB[128 * 40];
  const int tid  = threadIdx.x;
  const int lane = tid & 63;
  const int wave = tid >> 6;
  const int m0 = blockIdx.x * 128;
  const int n0 = blockIdx.y * 128;
  const int lr  = tid >> 2;
  const int lkc = (tid & 3) << 3;
  const int lm = lane & 15;
  const int lk = (lane >> 4) << 3;
  const int wrow = wave << 5;

  f32x4 acc[2][8];
  #pragma unroll
  for (int i = 0; i < 2; i++)
    #pragma unroll
    for (int j = 0; j < 8; j++) acc[i][j] = (f32x4){0.f, 0.f, 0.f, 0.f};

  const u16* aB0 = A16 + (size_t)(m0 + lr) * K + lkc;
  const u16* aB1 = A16 + (size_t)(m0 + lr + 64) * K + lkc;
  const u16* bB0 = Bt + (size_t)(n0 + lr) * K + lkc;
  const u16* bB1 = Bt + (size_t)(n0 + lr + 64) * K + lkc;

  uint4 rAa0, rAa1, rAb0, rAb1, rB0, rB1;

#define GSTORE(RA0, RA1) \
  { *(uint4*)(&lA[lr * 40 + lkc]) = RA0; \
    *(uint4*)(&lA[(lr + 64) * 40 + lkc]) = RA1; \
    *(uint4*)(&lB[lr * 40 + lkc]) = rB0; \
    *(uint4*)(&lB[(lr + 64) * 40 + lkc]) = rB1; }

#define GCOMP \
  { short8 a0 = *(const short8*)(&lA[(wrow + lm) * 40 + lk]); \
    short8 a1 = *(const short8*)(&lA[(wrow + 16 + lm) * 40 + lk]); \
    _Pragma("unroll") \
    for (int nj = 0; nj < 8; nj++){ \
      short8 b = *(const short8*)(&lB[(nj * 16 + lm) * 40 + lk]); \
      acc[0][nj] = __builtin_amdgcn_mfma_f32_16x16x32_bf16(a0, b, acc[0][nj], 0, 0, 0); \
      acc[1][nj] = __builtin_amdgcn_mfma_f32_16x16x32_bf16(a1, b, acc[1][nj], 0, 0, 0); \
    } }

  rAa0 = *(const uint4*)(aB0);
  rAa1 = *(const uint4*)(aB1);
  rAb0 = *(const uint4*)(aB0 + 32);
  rAb1 = *(const uint4*)(aB1 + 32);
  rB0  = *(const uint4*)(bB0);
  rB1  = *(const uint4*)(bB1);

  for (int k0 = 0; k0 < K; k0 += 64){
    // step A: K-tile k0 (A in rAa*, B in rB*)
    GSTORE(rAa0, rAa1);
    __syncthreads();
    rAa0 = *(const uint4*)(aB0 + k0 + 64);
    rAa1 = *(const uint4*)(aB1 + k0 + 64);
    rB0  = *(const uint4*)(bB0 + k0 + 32);
    rB1  = *(const uint4*)(bB1 + k0 + 32);
    GCOMP;
    __syncthreads();
    // step B: K-tile k0+32 (A in rAb*, B in rB*)
    GSTORE(rAb0, rAb1);
    __syncthreads();
    rAb0 = *(const uint4*)(aB0 + k0 + 96);
    rAb1 = *(const uint4*)(aB1 + k0 + 96);
    rB0  = *(const uint4*)(bB0 + k0 + 64);
    rB1  = *(const uint4*)(bB1 + k0 + 64);
    GCOMP;
    __syncthreads();
  }
#undef GSTORE
#undef GCOMP

  #pragma unroll
  for (int mi = 0; mi < 2; mi++)
    #pragma unroll
    for (int r4 = 0; r4 < 4; r4++){
      int row = wrow + mi * 16 + ((lane >> 4) << 2) + r4;
      int gm = m0 + row;
      if (gm < M){
        #pragma unroll
        for (int nj = 0; nj < 8; nj++){
          int gc = n0 + nj * 16 + lm;
          outBf[(size_t)gm * Ntot + gc] = f2bf(acc[mi][nj][r4] + bias[gc]);
        }
      }
    }
}

// ---------- fused edge GEMM: ea16[ETOT,384] x [W1e|W2e][384,320] ----------
// Distance-2 A prefetch (ping-pong named regs pAa/pAb; A is the HBM-cold
// stream), distance-1 B prefetch (L2-hot). K-loop = 6 explicit double-steps.
__global__ __launch_bounds__(256, 4)
void edge_k(const u16* __restrict__ ea16,   // [ETOT x 384] bf16 (edges + self loops)
            const u16* __restrict__ BtE,    // [320 x 384] bf16
            const int* __restrict__ rowA, const int* __restrict__ colA,
            const u16* __restrict__ XLR1,   // [NN x 512] bf16 = [xl1 | xr1]
            const float* __restrict__ att1, // [256] f32
            float* __restrict__ logit1,     // [ETOT x 4] f32
            u16* __restrict__ ep2)          // [ETOT x 64] bf16
{
  __shared__ __align__(16) u16 lA[64 * 40];
  __shared__ __align__(16) u16 lB[320 * 40];
  const int tid = threadIdx.x;
  const int lane = tid & 63;
  const int wave = tid >> 6;            // head 0..3
  const int m0 = blockIdx.x * 64;
  const int lm = lane & 15;
  const int lk = (lane >> 4) << 3;
  const int arow = tid >> 2;            // 0..63
  const int akc = (tid & 3) << 3;       // 0,8,16,24

  f32x4 acc[4][5];
  #pragma unroll
  for (int i = 0; i < 4; i++)
    #pragma unroll
    for (int j = 0; j < 5; j++) acc[i][j] = (f32x4){0.f, 0.f, 0.f, 0.f};

  const int gmA = m0 + arow;
  const u16* aBase = ea16 + (size_t)gmA * ED + akc;   // tail/over reads land in adjacent allocs
  const u16* bBase = BtE + (size_t)arow * ED + akc;

  uint4 pAa, pAb, pB0, pB1, pB2, pB3, pB4;

#define EISS_B(K0) \
  { const u16* bp = bBase + (K0); \
    pB0 = *(const uint4*)(bp); \
    pB1 = *(const uint4*)(bp + (size_t)64 * ED); \
    pB2 = *(const uint4*)(bp + (size_t)128 * ED); \
    pB3 = *(const uint4*)(bp + (size_t)192 * ED); \
    pB4 = *(const uint4*)(bp + (size_t)256 * ED); }

#define ESTORE(PA) \
  { *(uint4*)(&lA[arow * 40 + akc]) = PA; \
    *(uint4*)(&lB[(arow      ) * 40 + akc]) = pB0; \
    *(uint4*)(&lB[(arow +  64) * 40 + akc]) = pB1; \
    *(uint4*)(&lB[(arow + 128) * 40 + akc]) = pB2; \
    *(uint4*)(&lB[(arow + 192) * 40 + akc]) = pB3; \
    *(uint4*)(&lB[(arow + 256) * 40 + akc]) = pB4; }

#define ECOMP \
  { short8 a[4]; \
    _Pragma("unroll") \
    for (int mi = 0; mi < 4; mi++) a[mi] = *(const short8*)(&lA[(mi * 16 + lm) * 40 + lk]); \
    _Pragma("unroll") \
    for (int nj = 0; nj < 4; nj++){ \
      short8 b = *(const short8*)(&lB[(wave * 64 + nj * 16 + lm) * 40 + lk]); \
      _Pragma("unroll") \
      for (int mi = 0; mi < 4; mi++) \
        acc[mi][nj] = __builtin_amdgcn_mfma_f32_16x16x32_bf16(a[mi], b, acc[mi][nj], 0, 0, 0); \
    } \
    { short8 b = *(const short8*)(&lB[(256 + wave * 16 + lm) * 40 + lk]); \
      _Pragma("unroll") \
      for (int mi = 0; mi < 4; mi++) \
        acc[mi][4] = __builtin_amdgcn_mfma_f32_16x16x32_bf16(a[mi], b, acc[mi][4], 0, 0, 0); } }

  pAa = *(const uint4*)(aBase);
  pAb = *(const uint4*)(aBase + 32);
  EISS_B(0);

  for (int k0 = 0; k0 < ED; k0 += 64){
    // step A: K-tile k0 (A in pAa)
    ESTORE(pAa);
    __syncthreads();
    pAa = *(const uint4*)(aBase + k0 + 64);   // dist-2: consumed two steps later
    EISS_B(k0 + 32);
    ECOMP;
    __syncthreads();
    // step B: K-tile k0+32 (A in pAb)
    ESTORE(pAb);
    __syncthreads();
    pAb = *(const uint4*)(aBase + k0 + 96);
    EISS_B(k0 + 64);
    ECOMP;
    __syncthreads();
  }
#undef EISS_B
#undef ESTORE
#undef ECOMP

  float attc[4];
  #pragma unroll
  for (int nj = 0; nj < 4; nj++) attc[nj] = att1[wave * 64 + nj * 16 + lm];
  const int quad4 = (lane >> 4) << 2;
  #pragma unroll
  for (int mi = 0; mi < 4; mi++)
    #pragma unroll
    for (int r4 = 0; r4 < 4; r4++){
      int e = m0 + mi * 16 + quad4 + r4;
      float partial = 0.f;
      if (e < ETOT){
        int ii = (e < NE) ? rowA[e] : (e - NE);
        int jj = (e < NE) ? colA[e] : (e - NE);
        const u16* xlp = XLR1 + (size_t)jj * 512 + wave * 64;
        const u16* xrp = XLR1 + (size_t)ii * 512 + 256 + wave * 64;
        #pragma unroll
        for (int nj = 0; nj < 4; nj++){
          float v = acc[mi][nj][r4] + bf2f(xlp[nj * 16 + lm]) + bf2f(xrp[nj * 16 + lm]);
          v = (v > 0.f) ? v : 0.2f * v;
          partial += v * attc[nj];
        }
        ep2[(size_t)e * 64 + wave * 16 + lm] = f2bf(acc[mi][4][r4]);
      }
      partial += __shfl_xor(partial, 1);
      partial += __shfl_xor(partial, 2);
      partial += __shfl_xor(partial, 4);
      partial += __shfl_xor(partial, 8);
      if (lm == 0 && e < ETOT) logit1[(size_t)e * 4 + wave] = partial;
    }
}

// ---------- layer-2 logit epilogue ----------
__global__ __launch_bounds__(256) void logit2_k(const int* __restrict__ rowA,
    const int* __restrict__ colA, const u16* __restrict__ ep2,
    const u16* __restrict__ XLR2,   // [NN x 128] = [xl2 | xr2]
    const float* __restrict__ att2, float* __restrict__ logit2)
{
  int e = blockIdx.x * 16 + (threadIdx.x >> 4);
  if (e >= ETOT) return;
  int lm = threadIdx.x & 15;
  int ii = (e < NE) ? rowA[e] : (e - NE);
  int jj = (e < NE) ? colA[e] : (e - NE);
  ushort4 pe = *(const ushort4*)(ep2 + (size_t)e * 64 + lm * 4);
  ushort4 pl = *(const ushort4*)(XLR2 + (size_t)jj * 128 + lm * 4);
  ushort4 pr = *(const ushort4*)(XLR2 + (size_t)ii * 128 + 64 + lm * 4);
  float s = 0.f;
  float v0 = bf2f(pe.x) + bf2f(pl.x) + bf2f(pr.x); v0 = v0 > 0.f ? v0 : 0.2f * v0;
  float v1 = bf2f(pe.y) + bf2f(pl.y) + bf2f(pr.y); v1 = v1 > 0.f ? v1 : 0.2f * v1;
  float v2 = bf2f(pe.z) + bf2f(pl.z) + bf2f(pr.z); v2 = v2 > 0.f ? v2 : 0.2f * v2;
  float v3 = bf2f(pe.w) + bf2f(pl.w) + bf2f(pr.w); v3 = v3 > 0.f ? v3 : 0.2f * v3;
  s = v0 * att2[lm * 4] + v1 * att2[lm * 4 + 1] + v2 * att2[lm * 4 + 2] + v3 * att2[lm * 4 + 3];
  s += __shfl_xor(s, 1);
  s += __shfl_xor(s, 2);
  s += __shfl_xor(s, 4);
  s += __shfl_xor(s, 8);
  if (lm == 0) logit2[e] = s;
}

// ---------- segment softmax + aggregation, layer 1 (H=4, C=64), x2 unroll ----------
__global__ __launch_bounds__(256) void agg1_k(const int* __restrict__ rowPtr,
    const int* __restrict__ rowIdx, const float4* __restrict__ lg4,
    const u16* __restrict__ XL1, int xstride, const int* __restrict__ colA,
    const float* __restrict__ bias1, u16* __restrict__ H1)
{
  int node = blockIdx.x * 4 + (threadIdx.x >> 6);
  if (node >= NN) return;
  int lane = threadIdx.x & 63;
  int p0 = rowPtr[node], deg = rowPtr[node + 1] - p0;
  float4 sl = lg4[NE + node];
  float m0 = sl.x, m1 = sl.y, m2 = sl.z, m3 = sl.w;
  for (int t = lane; t < deg; t += 64){
    float4 l = lg4[rowIdx[p0 + t]];
    m0 = fmaxf(m0, l.x); m1 = fmaxf(m1, l.y); m2 = fmaxf(m2, l.z); m3 = fmaxf(m3, l.w);
  }
  #pragma unroll
  for (int off = 32; off > 0; off >>= 1){
    m0 = fmaxf(m0, __shfl_xor(m0, off));
    m1 = fmaxf(m1, __shfl_xor(m1, off));
    m2 = fmaxf(m2, __shfl_xor(m2, off));
    m3 = fmaxf(m3, __shfl_xor(m3, off));
  }
  float d0, d1, d2, d3, a0, a1, a2, a3;
  {
    float e0 = __expf(sl.x - m0), e1 = __expf(sl.y - m1), e2 = __expf(sl.z - m2), e3 = __expf(sl.w - m3);
    d0 = e0; d1 = e1; d2 = e2; d3 = e3;
    const u16* xp = XL1 + (size_t)node * xstride;
    a0 = e0 * bf2f(xp[lane]); a1 = e1 * bf2f(xp[64 + lane]);
    a2 = e2 * bf2f(xp[128 + lane]); a3 = e3 * bf2f(xp[192 + lane]);
  }
  int t = 0;
  for (; t + 1 < deg; t += 2){
    int eA = rowIdx[p0 + t];
    int eB = rowIdx[p0 + t + 1];
    float4 lA_ = lg4[eA];
    float4 lB_ = lg4[eB];
    int jA = colA[eA];
    int jB = colA[eB];
    const u16* xa = XL1 + (size_t)jA * xstride;
    const u16* xb = XL1 + (size_t)jB * xstride;
    float eA0 = __expf(lA_.x - m0), eA1 = __expf(lA_.y - m1), eA2 = __expf(lA_.z - m2), eA3 = __expf(lA_.w - m3);
    float eB0 = __expf(lB_.x - m0), eB1 = __expf(lB_.y - m1), eB2 = __expf(lB_.z - m2), eB3 = __expf(lB_.w - m3);
    d0 += eA0 + eB0; d1 += eA1 + eB1; d2 += eA2 + eB2; d3 += eA3 + eB3;
    a0 += eA0 * bf2f(xa[lane])       + eB0 * bf2f(xb[lane]);
    a1 += eA1 * bf2f(xa[64 + lane])  + eB1 * bf2f(xb[64 + lane]);
    a2 += eA2 * bf2f(xa[128 + lane]) + eB2 * bf2f(xb[128 + lane]);
    a3 += eA3 * bf2f(xa[192 + lane]) + eB3 * bf2f(xb[192 + lane]);
  }
  if (t < deg){
    int e = rowIdx[p0 + t];
    float4 l = lg4[e];
    int j = colA[e];
    float e0 = __expf(l.x - m0), e1 = __expf(l.y - m1), e2 = __expf(l.z - m2), e3 = __expf(l.w - m3);
    d0 += e0; d1 += e1; d2 += e2; d3 += e3;
    const u16* xp = XL1 + (size_t)j * xstride;
    a0 += e0 * bf2f(xp[lane]); a1 += e1 * bf2f(xp[64 + lane]);
    a2 += e2 * bf2f(xp[128 + lane]); a3 += e3 * bf2f(xp[192 + lane]);
  }
  float v0 = a0 / d0 + bias1[lane];
  float v1 = a1 / d1 + bias1[64 + lane];
  float v2 = a2 / d2 + bias1[128 + lane];
  float v3 = a3 / d3 + bias1[192 + lane];
  v0 = v0 > 0.f ? v0 : 0.01f * v0;
  v1 = v1 > 0.f ? v1 : 0.01f * v1;
  v2 = v2 > 0.f ? v2 : 0.01f * v2;
  v3 = v3 > 0.f ? v3 : 0.01f * v3;
  u16* hp = H1 + (size_t)node * NH1;
  hp[lane] = f2bf(v0); hp[64 + lane] = f2bf(v1);
  hp[128 + lane] = f2bf(v2); hp[192 + lane] = f2bf(v3);
}

// ---------- layer 2 softmax+agg (H=1, C=64), x2 unroll ----------
__global__ __launch_bounds__(256) void agg2_k(const int* __restrict__ rowPtr,
    const int* __restrict__ rowIdx, const float* __restrict__ lg,
    const u16* __restrict__ XL2, int xstride, const int* __restrict__ colA,
    const float* __restrict__ bias2, float* __restrict__ H2)
{
  int node = blockIdx.x * 4 + (threadIdx.x >> 6);
  if (node >= NN) return;
  int lane = threadIdx.x & 63;
  int p0 = rowPtr[node], deg = rowPtr[node + 1] - p0;
  float sl = lg[NE + node];
  float mx = sl;
  for (int t = lane; t < deg; t += 64) mx = fmaxf(mx, lg[rowIdx[p0 + t]]);
  #pragma unroll
  for (int off = 32; off > 0; off >>= 1) mx = fmaxf(mx, __shfl_xor(mx, off));
  float den = __expf(sl - mx);
  float acc = den * bf2f(XL2[(size_t)node * xstride + lane]);
  int t = 0;
  for (; t + 1 < deg; t += 2){
    int eA = rowIdx[p0 + t];
    int eB = rowIdx[p0 + t + 1];
    float exA = __expf(lg[eA] - mx);
    float exB = __expf(lg[eB] - mx);
    int jA = colA[eA];
    int jB = colA[eB];
    den += exA + exB;
    acc += exA * bf2f(XL2[(size_t)jA * xstride + lane])
         + exB * bf2f(XL2[(size_t)jB * xstride + lane]);
  }
  if (t < deg){
    int e = rowIdx[p0 + t];
    float ex = __expf(lg[e] - mx);
    den += ex;
    acc += ex * bf2f(XL2[(size_t)colA[e] * xstride + lane]);
  }
  float v = acc / den + bias2[lane];
  v = v > 0.f ? v : 0.01f * v;
  H2[(size_t)node * 64 + lane] = v;
}

// ---------- global max pool + LayerNorm (C=64), 4 waves/block ----------
__global__ __launch_bounds__(256) void poolln_k(const float* __restrict__ H2,
    const float* __restrict__ lng, const float* __restrict__ lnb, float* __restrict__ outGn)
{
  __shared__ float sm[4][64];
  int g = blockIdx.x, w = threadIdx.x >> 6, c = threadIdx.x & 63;
  int beg = (g * NN + NG - 1) / NG;
  int end = ((g + 1) * NN + NG - 1) / NG;
  float m = -3.0e38f;
  for (int n = beg + w; n < end; n += 4) m = fmaxf(m, H2[(size_t)n * 64 + c]);
  sm[w][c] = m;
  __syncthreads();
  if (threadIdx.x < 64){
    m = fmaxf(fmaxf(sm[0][c], sm[1][c]), fmaxf(sm[2][c], sm[3][c]));
    float s = m;
    #pragma unroll
    for (int off = 32; off > 0; off >>= 1) s += __shfl_xor(s, off);
    float mu = s * (1.f / 64.f);
    float d = m - mu;
    float vv = d * d;
    #pragma unroll
    for (int off = 32; off > 0; off >>= 1) vv += __shfl_xor(vv, off);
    float var = vv * (1.f / 64.f);
    outGn[g * 64 + c] = d * rsqrtf(var + 1e-5f) * lng[c] + lnb[c];
  }
}

// ---------- classifier [G,64] @ [64,751] + b ----------
__global__ __launch_bounds__(256) void clf_k(const float* __restrict__ gn,
    const float* __restrict__ W, const float* __restrict__ b, float* __restrict__ outCls)
{
  __shared__ float sg[64];
  int g = blockIdx.x;
  if (threadIdx.x < 64) sg[threadIdx.x] = gn[g * 64 + threadIdx.x];
  __syncthreads();
  for (int o = threadIdx.x; o < NCLS; o += 256){
    float s = b[o];
    #pragma unroll 16
    for (int c = 0; c < 64; c++) s += sg[c] * W[c * NCLS + o];
    outCls[(size_t)g * NCLS + o] = s;
  }
}

extern "C" void kernel_launch(void* const* d_in, const int* in_sizes, int n_in,
                              void* d_out, int out_size, void* d_ws, size_t ws_size,
                              hipStream_t stream)
{
  const float* x     = (const float*)d_in[0];
  const int*   eidx  = (const int*)d_in[1];
  const float* eattr = (const float*)d_in[2];
  const float* W1l = (const float*)d_in[4];
  const float* b1l = (const float*)d_in[5];
  const float* W1r = (const float*)d_in[6];
  const float* b1r = (const float*)d_in[7];
  const float* W1e = (const float*)d_in[8];
  const float* att1 = (const float*)d_in[9];
  const float* bias1 = (const float*)d_in[10];
  const float* W2l = (const float*)d_in[11];
  const float* b2l = (const float*)d_in[12];
  const float* W2r = (const float*)d_in[13];
  const float* b2r = (const float*)d_in[14];
  const float* W2e = (const float*)d_in[15];
  const float* att2 = (const float*)d_in[16];
  const float* bias2 = (const float*)d_in[17];
  const float* lng = (const float*)d_in[18];
  const float* lnb = (const float*)d_in[19];
  const float* clfW = (const float*)d_in[20];
  const float* clfb = (const float*)d_in[21];
  const int* rowA = eidx;        // ei_i (aggregation target)
  const int* colA = eidx + NE;   // ei_j (message source)

  char* w = (char*)d_ws;
  auto alloc = [&](size_t b) -> char* {
    char* p = w; w += (b + 255) & ~(size_t)255; return p;
  };
  u16* W1lrT  = (u16*)alloc((size_t)512 * 512 * 2);   // [512 cols x 512 K]
  u16* BtE    = (u16*)alloc((size_t)320 * ED * 2);    // [W1e|W2e]^T
  u16* W2lrT  = (u16*)alloc((size_t)128 * 256 * 2);
  float* biasLR1 = (float*)alloc(512 * 4);
  float* biasLR2 = (float*)alloc(128 * 4);
  int* degR   = (int*)alloc((size_t)NN * 4);
  int* degC   = (int*)alloc((size_t)NN * 4);
  int* rowPtr = (int*)alloc((size_t)(NN + 1) * 4);
  int* colPtr = (int*)alloc((size_t)(NN + 1) * 4);
  int* rowCur = (int*)alloc((size_t)NN * 4);
  int* colCur = (int*)alloc((size_t)NN * 4);
  int* rowIdx = (int*)alloc((size_t)NE * 4);
  int* colIdx = (int*)alloc((size_t)NE * 4);
  u16* ea16   = (u16*)alloc((size_t)ETOT * ED * 2);   // 169 MB: bf16 edges + self loops
  u16* x16    = (u16*)alloc((size_t)NN * 512 * 2);    // bf16 x (absorbs edge_k/gemm tail OOB reads)
  u16* XLR1   = (u16*)alloc((size_t)NN * 512 * 2);
  float* logit1 = (float*)alloc((size_t)ETOT * 4 * 4);
  u16* H1     = (u16*)alloc((size_t)NN * NH1 * 2);
  u16* ep2    = (u16*)alloc((size_t)ETOT * 64 * 2);
  // aliased into ea16 (ea16's last reader is edge_k):
  u16* XLR2   = (u16*)ea16;                                  // 5.12 MB
  float* logit2 = (float*)((char*)ea16 + (size_t)5500928);   // 0.88 MB
  float* H2   = (float*)((char*)ea16 + (size_t)6553600);     // 5.12 MB

  hipMemsetAsync(degR, 0, (size_t)NN * 4, stream);
  hipMemsetAsync(degC, 0, (size_t)NN * 4, stream);
  hipMemsetAsync(rowCur, 0, (size_t)NN * 4, stream);
  hipMemsetAsync(colCur, 0, (size_t)NN * 4, stream);

  transpose_k<<<(512 * 256 + 255) / 256, 256, 0, stream>>>(W1l, W1lrT, 512, 256);
  transpose_k<<<(512 * 256 + 255) / 256, 256, 0, stream>>>(W1r, W1lrT + (size_t)256 * 512, 512, 256);
  transpose_k<<<(ED * 256 + 255) / 256, 256, 0, stream>>>(W1e, BtE, ED, 256);
  transpose_k<<<(ED * 64 + 255) / 256, 256, 0, stream>>>(W2e, BtE + (size_t)256 * ED, ED, 64);
  transpose_k<<<(256 * 64 + 255) / 256, 256, 0, stream>>>(W2l, W2lrT, 256, 64);
  transpose_k<<<(256 * 64 + 255) / 256, 256, 0, stream>>>(W2r, W2lrT + (size_t)64 * 256, 256, 64);
  concatbias_k<<<3, 256, 0, stream>>>(b1l, b1r, b2l, b2r, biasLR1, biasLR2);
  convx_k<<<(NN * 512 / 8 + 255) / 256, 256, 0, stream>>>(x, x16, NN * 512 / 8);

  hist_k<<<(NE + 255) / 256, 256, 0, stream>>>(rowA, colA, degR, degC);
  scan_k<<<1, 256, 0, stream>>>(degR, degC, rowPtr, colPtr);
  scatter_k<<<(NE + 255) / 256, 256, 0, stream>>>(rowA, colA, rowPtr, colPtr,
                                                  rowCur, colCur, rowIdx, colIdx);
  loopattr_k<<<(NN + 3) / 4, 256, 0, stream>>>(colPtr, colIdx, eattr, ea16);

  // XLR1 = x @ [W1l|W1r] + [b1l|b1r]  -> [NN, 512] bf16
  dim3 gx1((NN + 127) / 128, 4);
  gemm_k<<<gx1, 256, 0, stream>>>(x16, W1lrT, NN, 512, 512, biasLR1, XLR1);
  // fused edge GEMM: logit1 + ep2
  edge_k<<<(ETOT + 63) / 64, 256, 0, stream>>>(ea16, BtE, rowA, colA,
                                               XLR1, att1, logit1, ep2);
  agg1_k<<<(NN + 3) / 4, 256, 0, stream>>>(rowPtr, rowIdx, (const float4*)logit1,
                                           XLR1, 512, colA, bias1, H1);
  // XLR2 = H1 @ [W2l|W2r] + [b2l|b2r]  -> [NN, 128] bf16
  dim3 gx2((NN + 127) / 128, 1);
  gemm_k<<<gx2, 256, 0, stream>>>(H1, W2lrT, NN, 256, 128, biasLR2, XLR2);
  logit2_k<<<(ETOT + 15) / 16, 256, 0, stream>>>(rowA, colA, ep2, XLR2, att2, logit2);
  agg2_k<<<(NN + 3) / 4, 256, 0, stream>>>(rowPtr, rowIdx, logit2, XLR2, 128, colA, bias2, H2);

  float* outCls = (float*)d_out;
  float* outGn  = outCls + (size_t)NG * NCLS;
  poolln_k<<<NG, 256, 0, stream>>>(H2, lng, lnb, outGn);
  clf_k<<<NG, 256, 0, stream>>>(outGn, clfW, clfb, outCls);
}